// Round 13
// baseline (301.656 us; speedup 1.0000x reference)
//
#include <hip/hip_runtime.h>
#include <hip/hip_bf16.h>
#include <math.h>

#define B 16
#define S 200
#define IN 128
#define H 128
#define NK 11      // K+1 buckets
#define OUTN 10000
#define H4 512

// ---------------- proj GEMMs (embed fused): P[r,kb,:] = table[seq[r],:] @ W[kb] ----------------
__global__ __launch_bounds__(512) void k_proj(
        const int* __restrict__ seq, const float* __restrict__ table,
        const int* __restrict__ length,
        const float* __restrict__ tw, const float* __restrict__ dw,
        float* __restrict__ pt, float* __restrict__ pd) {
    __shared__ float xs[32][68];    // [k][r], padded so xs[k][4*tr] is 16B aligned
    __shared__ float wsm[32][128];  // [k][c]
    __shared__ int sneed;
    int tid = threadIdx.x;
    int r0blk = blockIdx.x * 64;
    if (tid == 0) sneed = 0;
    __syncthreads();
    if (tid < 64) {
        int r = r0blk + tid;
        int bb = r / S, ii = r - bb * S;
        if (ii < length[bb]) sneed = 1;   // benign same-value race
    }
    __syncthreads();
    if (!sneed) return;

    int which = blockIdx.y / NK;
    int kb = blockIdx.y % NK;
    const float* W = (which == 0 ? tw : dw) + kb * IN * H;
    float* P = (which == 0 ? pt : pd);
    int tr = tid >> 5;          // 0..15 (row group)
    int tc = tid & 31;          // 0..31 (col group)
    int rr0 = tr * 4;

    float acc[4][4] = {{0.f}};
    for (int kk = 0; kk < IN; kk += 32) {
        {   // load x tile via embed gather (transposed into xs[k][r])
            int r = tid >> 3;              // 0..63
            int kq = (tid & 7) * 4;        // 0,4,..,28
            int sv = seq[r0blk + r];
            float4 v = *reinterpret_cast<const float4*>(&table[sv * IN + kk + kq]);
            xs[kq + 0][r] = v.x; xs[kq + 1][r] = v.y;
            xs[kq + 2][r] = v.z; xs[kq + 3][r] = v.w;
        }
        #pragma unroll
        for (int i = 0; i < 2; ++i) {       // load W chunk [32][128]
            int f = tid + i * 512;          // float4 index 0..1023
            int k = f >> 5; int c4 = f & 31;
            *reinterpret_cast<float4*>(&wsm[k][c4 * 4]) =
                *reinterpret_cast<const float4*>(&W[(kk + k) * H + c4 * 4]);
        }
        __syncthreads();
        #pragma unroll
        for (int k = 0; k < 32; ++k) {
            float4 a = *reinterpret_cast<const float4*>(&xs[k][rr0]);
            float4 w = *reinterpret_cast<const float4*>(&wsm[k][tc * 4]);
            acc[0][0] += a.x * w.x; acc[0][1] += a.x * w.y; acc[0][2] += a.x * w.z; acc[0][3] += a.x * w.w;
            acc[1][0] += a.y * w.x; acc[1][1] += a.y * w.y; acc[1][2] += a.y * w.z; acc[1][3] += a.y * w.w;
            acc[2][0] += a.z * w.x; acc[2][1] += a.z * w.y; acc[2][2] += a.z * w.z; acc[2][3] += a.z * w.w;
            acc[3][0] += a.w * w.x; acc[3][1] += a.w * w.y; acc[3][2] += a.w * w.z; acc[3][3] += a.w * w.w;
        }
        __syncthreads();
    }
    #pragma unroll
    for (int i = 0; i < 4; ++i) {
        int r = r0blk + rr0 + i;
        float4 v = make_float4(acc[i][0], acc[i][1], acc[i][2], acc[i][3]);
        *reinterpret_cast<float4*>(&P[(r * NK + kb) * H + tc * 4]) = v;
    }
}

// ---------------- X[b,i,:] = 0.5 * sum_j (P_t[b,j,tk] + P_d[b,j,dk]) ----------------
__global__ __launch_bounds__(512) void k_xsum(const float* __restrict__ pt, const float* __restrict__ pd,
                       const int* __restrict__ length, const float* __restrict__ ts,
                       const float* __restrict__ lat, const float* __restrict__ lng,
                       float* __restrict__ X) {
    int wg = blockIdx.x;
    int idx = wg >> 3;                    // 0..399
    int b = (wg & 7) + 8 * (idx / S);     // XCD x serves batches {x, x+8}: L2 locality
    int i = idx % S;
    int len = length[b];
    if (i >= len) return;
    __shared__ float sts[S], sla[S], sln[S];
    __shared__ float psum[16][128];
    int tid = threadIdx.x;
    int jg = tid >> 5, c = tid & 31;
    if (tid < S) {
        sts[tid] = ts[b * S + tid]; sla[tid] = lat[b * S + tid]; sln[tid] = lng[b * S + tid];
    }
    __syncthreads();
    float ti = sts[i], lai = sla[i], lni = sln[i];
    float4 at = make_float4(0.f, 0.f, 0.f, 0.f);
    float4 ad = make_float4(0.f, 0.f, 0.f, 0.f);
    const float* ptb = pt + (b * S) * NK * H;
    const float* pdb = pd + (b * S) * NK * H;
    for (int j = jg; j <= i; j += 16) {       // interleaved for group load balance
        float td = ti - sts[j];
        if (td < 0.f || td > 1.f) continue;   // exact reference window
        int tk = (int)(td * 10.f); if (tk > 10) tk = 10;    // td>=0: cast==floor
        float dx = lai - sla[j], dy = lni - sln[j];
        float dist = sqrtf(dx * dx + dy * dy);
        int dk = (int)(dist * 10.f); if (dk > 10) dk = 10;  // matches clip->*10->floor
        float4 vt = *((const float4*)&ptb[(j * NK + tk) * H] + c);
        float4 vd = *((const float4*)&pdb[(j * NK + dk) * H] + c);
        at.x += vt.x; at.y += vt.y; at.z += vt.z; at.w += vt.w;
        ad.x += vd.x; ad.y += vd.y; ad.z += vd.z; ad.w += vd.w;
    }
    float4 s4 = make_float4(at.x + ad.x, at.y + ad.y, at.z + ad.z, at.w + ad.w);
    *reinterpret_cast<float4*>(&psum[jg][c * 4]) = s4;
    __syncthreads();
    if (tid < H) {
        float s = 0.f;
        #pragma unroll
        for (int g = 0; g < 16; ++g) s += psum[g][tid];
        X[(b * S + i) * H + tid] = 0.5f * s;
    }
}

// ---------------- RNN + fused FC1 ----------------
// grid B, block 128 (2 waves). LDS-BW-bound fix: 4 outputs/thread amortizes the h-broadcast
// (64KB -> 16KB per step on the DS pipe). lane = (og_local<<2)|kg: og = wv*16+og_local (4 outputs
// o0=og*4..+3), kg = 4-way k-split (32 h each, kg-staggered b128 reads -> conflict-free).
// After the 2-stage shfl_xor butterfly ALL lanes hold all 4 sums; lane finishes output q=kg
// (1 exp + 1 b32 write per lane). One barrier/step. Weights: 128 VGPR/thread.
__global__ __launch_bounds__(128) void k_rnn(const float* __restrict__ X,
        const float* __restrict__ Wh, const int* __restrict__ length,
        const float* __restrict__ W1, const float* __restrict__ b1,
        float* __restrict__ t1) {
    __shared__ float xlds[S * H];     // 100 KB
    __shared__ float hbuf[2][H];
    int b = blockIdx.x;
    int len = length[b];
    int tid = threadIdx.x;        // 0..127
    int lane = tid & 63;
    int wv = tid >> 6;            // 0..1
    int og = wv * 16 + (lane >> 2);  // 0..31
    int kg = lane & 3;            // 0..3
    int o0 = og * 4;
    // w4[it][q] = Wh[k0..k0+3][o0+q] over the kg-staggered k-order, k0 = kg*32+((it^kg)&7)*4
    float4 w4[8][4];
    #pragma unroll
    for (int it = 0; it < 8; ++it) {
        int k0 = kg * 32 + ((it ^ kg) & 7) * 4;
        #pragma unroll
        for (int q = 0; q < 4; ++q) {
            w4[it][q].x = Wh[(k0 + 0) * H + o0 + q];
            w4[it][q].y = Wh[(k0 + 1) * H + o0 + q];
            w4[it][q].z = Wh[(k0 + 2) * H + o0 + q];
            w4[it][q].w = Wh[(k0 + 3) * H + o0 + q];
        }
    }
    {   // stage X[b] -> LDS (coalesced float4)
        const float4* Xb4 = reinterpret_cast<const float4*>(X + b * S * H);
        float4* xl4 = reinterpret_cast<float4*>(xlds);
        for (int idx = tid; idx < S * H / 4; idx += 128) xl4[idx] = Xb4[idx];
    }
    if (tid < H) hbuf[0][tid] = 0.f;
    __syncthreads();
    int cur = 0;
    for (int i = 0; i < len; ++i) {
        const float* hb = &hbuf[cur][kg * 32];
        float4 a0 = make_float4(0.f,0.f,0.f,0.f), a1 = a0, a2 = a0, a3 = a0;
        #pragma unroll
        for (int it = 0; it < 8; ++it) {
            float4 hv = *reinterpret_cast<const float4*>(&hb[((it ^ kg) & 7) * 4]);
            a0.x += hv.x * w4[it][0].x; a0.y += hv.y * w4[it][0].y; a0.z += hv.z * w4[it][0].z; a0.w += hv.w * w4[it][0].w;
            a1.x += hv.x * w4[it][1].x; a1.y += hv.y * w4[it][1].y; a1.z += hv.z * w4[it][1].z; a1.w += hv.w * w4[it][1].w;
            a2.x += hv.x * w4[it][2].x; a2.y += hv.y * w4[it][2].y; a2.z += hv.z * w4[it][2].z; a2.w += hv.w * w4[it][2].w;
            a3.x += hv.x * w4[it][3].x; a3.y += hv.y * w4[it][3].y; a3.z += hv.z * w4[it][3].z; a3.w += hv.w * w4[it][3].w;
        }
        float p0 = (a0.x + a0.y) + (a0.z + a0.w);
        float p1 = (a1.x + a1.y) + (a1.z + a1.w);
        float p2 = (a2.x + a2.y) + (a2.z + a2.w);
        float p3 = (a3.x + a3.y) + (a3.z + a3.w);
        p0 += __shfl_xor(p0, 1); p0 += __shfl_xor(p0, 2);
        p1 += __shfl_xor(p1, 1); p1 += __shfl_xor(p1, 2);
        p2 += __shfl_xor(p2, 1); p2 += __shfl_xor(p2, 2);
        p3 += __shfl_xor(p3, 1); p3 += __shfl_xor(p3, 2);
        float p = (kg == 0) ? p0 : (kg == 1) ? p1 : (kg == 2) ? p2 : p3;
        float xc = xlds[i * H + o0 + kg];
        float hn = 1.f / (1.f + __expf(-(xc + p)));
        hbuf[cur ^ 1][o0 + kg] = hn;
        __syncthreads();
        cur ^= 1;
    }
    // fused fc1: 4 outputs/thread, coalesced W1 reads, hfin broadcast from LDS
    const float* hfin = hbuf[cur];
    float c0 = b1[tid], c1 = b1[tid + 128], c2 = b1[tid + 256], c3 = b1[tid + 384];
    for (int k = 0; k < H; ++k) {
        float hv = hfin[k];
        const float* wr = &W1[k * H4 + tid];
        c0 += hv * wr[0]; c1 += hv * wr[128]; c2 += hv * wr[256]; c3 += hv * wr[384];
    }
    t1[b * H4 + tid]       = tanhf(c0);
    t1[b * H4 + tid + 128] = tanhf(c1);
    t1[b * H4 + tid + 256] = tanhf(c2);
    t1[b * H4 + tid + 384] = tanhf(c3);
}

// ---------------- FC2: out[b,o] = t1[b,:] @ W2[:,o] + b2[o] ----------------
__global__ __launch_bounds__(256) void k_fc2(const float* __restrict__ t1,
        const float* __restrict__ W2, const float* __restrict__ b2,
        float* __restrict__ out) {
    __shared__ float tls[H4 * B];   // [k][b] layout, 32KB
    int tid = threadIdx.x;
    int o = blockIdx.x * 64 + (tid & 63);
    int bq = tid >> 6;              // 0..3
    for (int idx = tid; idx < H4 * B; idx += 256) {
        int k = idx >> 4, bb = idx & 15;
        tls[idx] = t1[bb * H4 + k];
    }
    __syncthreads();
    if (o >= OUTN) return;
    float a0 = 0.f, a1 = 0.f, a2 = 0.f, a3 = 0.f;
    for (int k = 0; k < H4; ++k) {
        float wv = W2[k * OUTN + o];
        const float* tk = &tls[k * 16 + bq * 4];
        a0 += wv * tk[0]; a1 += wv * tk[1]; a2 += wv * tk[2]; a3 += wv * tk[3];
    }
    float bb2 = b2[o];
    out[(bq * 4 + 0) * OUTN + o] = a0 + bb2;
    out[(bq * 4 + 1) * OUTN + o] = a1 + bb2;
    out[(bq * 4 + 2) * OUTN + o] = a2 + bb2;
    out[(bq * 4 + 3) * OUTN + o] = a3 + bb2;
}

extern "C" void kernel_launch(void* const* d_in, const int* in_sizes, int n_in,
                              void* d_out, int out_size, void* d_ws, size_t ws_size,
                              hipStream_t stream) {
    const int*   seq    = (const int*)d_in[0];
    const int*   length = (const int*)d_in[1];
    const float* ts     = (const float*)d_in[2];
    const float* lat    = (const float*)d_in[3];
    const float* lng    = (const float*)d_in[4];
    const float* table  = (const float*)d_in[5];
    const float* tw     = (const float*)d_in[6];
    const float* dw     = (const float*)d_in[7];
    const float* wh     = (const float*)d_in[8];
    const float* W1     = (const float*)d_in[9];
    const float* b1     = (const float*)d_in[10];
    const float* W2     = (const float*)d_in[11];
    const float* b2     = (const float*)d_in[12];
    float* out = (float*)d_out;

    float* wsf  = (float*)d_ws;
    float* pt   = wsf;                       // B*S*NK*H = 4505600
    float* pd   = pt + B * S * NK * H;       // B*S*NK*H = 4505600
    float* X    = pd + B * S * NK * H;       // B*S*H    = 409600
    float* t1   = X  + B * S * H;            // B*H4     = 8192

    k_proj<<<dim3((B * S) / 64, 2 * NK), 512, 0, stream>>>(seq, table, length, tw, dw, pt, pd);
    k_xsum<<<B * S, 512, 0, stream>>>(pt, pd, length, ts, lat, lng, X);
    k_rnn<<<B, 128, 0, stream>>>(X, wh, length, W1, b1, t1);
    k_fc2<<<(OUTN + 63) / 64, 256, 0, stream>>>(t1, W2, b2, out);
}